// Round 4
// baseline (163.278 us; speedup 1.0000x reference)
//
#include <hip/hip_runtime.h>

// Problem constants (fixed by setup_inputs).
constexpr int Bn = 512;               // batch rows
constexpr int Ln = 512;               // sequence length
constexpr int Fn = 64;                // feature dim
constexpr int Vn = 20000;             // num_nodes (vocab)
constexpr int HWORDS = (Vn + 2) / 3;  // 10-bit-packed histogram words (3 counts/u32)
constexpr int BL = Bn * Ln;           // positions per channel = 262144 = 2^18

// clang-native float4 (HIP's float4 is a class the nontemporal builtin rejects)
typedef float f32x4 __attribute__((ext_vector_type(4)));

__device__ __forceinline__ unsigned hist_get(const unsigned* __restrict__ h, int v) {
    const int w = v / 3;
    const int f = v - w * 3;
    return (h[w] >> (10 * f)) & 0x3FFu;
}

// Kernel 1: per-row LDS histograms -> packed per-position counts (2 MB),
// with the 513-row MLP table build folded in (block b computes table row b;
// block 511 also row 512).
// table[v][j] = sum_i relu(v*W1[i] + b1[i]) * W2[i*Fn + j] + b2[j]
__global__ __launch_bounds__(256) void prep_kernel(
    const int* __restrict__ src_ids,
    const int* __restrict__ dst_ids,
    const float* __restrict__ W1,
    const float* __restrict__ b1,
    const float* __restrict__ W2,
    const float* __restrict__ b2,
    float* __restrict__ table,
    unsigned* __restrict__ counts) {
    __shared__ unsigned hs[HWORDS];
    __shared__ unsigned hd[HWORDS];

    const int b = blockIdx.x;
    const int tid = threadIdx.x;

    for (int i = tid; i < HWORDS; i += 256) { hs[i] = 0u; hd[i] = 0u; }

    // Table rows (no LDS use; runs while other waves finish the clear).
    if (tid < Fn) {
        const int j = tid;
        const float v = (float)b;
        float acc = b2[j];
#pragma unroll
        for (int i = 0; i < Fn; ++i) {
            const float h = fmaxf(fmaf(v, W1[i], b1[i]), 0.0f);
            acc = fmaf(h, W2[i * Fn + j], acc);
        }
        table[b * Fn + j] = acc;
    }
    if (b == Bn - 1 && tid >= 64 && tid < 64 + Fn) {  // row 512, wave 1
        const int j = tid - 64;
        const float v = (float)Ln;
        float acc = b2[j];
#pragma unroll
        for (int i = 0; i < Fn; ++i) {
            const float h = fmaxf(fmaf(v, W1[i], b1[i]), 0.0f);
            acc = fmaf(h, W2[i * Fn + j], acc);
        }
        table[Ln * Fn + j] = acc;
    }
    __syncthreads();

    const int* __restrict__ srow = src_ids + b * Ln;
    const int* __restrict__ drow = dst_ids + b * Ln;

    // Ln == 512 == 2*blockDim: each thread owns positions tid and tid+256.
    const int s0 = srow[tid], s1 = srow[tid + 256];
    const int d0 = drow[tid], d1 = drow[tid + 256];
    {
        int w;
        w = s0 / 3; atomicAdd(&hs[w], 1u << (10 * (s0 - w * 3)));
        w = s1 / 3; atomicAdd(&hs[w], 1u << (10 * (s1 - w * 3)));
        w = d0 / 3; atomicAdd(&hd[w], 1u << (10 * (d0 - w * 3)));
        w = d1 / 3; atomicAdd(&hd[w], 1u << (10 * (d1 - w * 3)));
    }
    __syncthreads();

    // Packed counts: (count in src row) | (count in dst row) << 16.
    // Padding id 0 -> 0 in both channels (matches reference masking).
    const size_t base = (size_t)b * Ln;
#pragma unroll
    for (int k = 0; k < 2; ++k) {
        const int l = tid + k * 256;
        const int s = (k == 0) ? s0 : s1;
        const int d = (k == 0) ? d0 : d1;
        unsigned ws = 0u, wd = 0u;
        if (s != 0) ws = hist_get(hs, s) | (hist_get(hd, s) << 16);
        if (d != 0) wd = hist_get(hs, d) | (hist_get(hd, d) << 16);
        counts[base + l] = ws;
        counts[BL + base + l] = wd;
    }
}

// Kernel 2: pure streaming expansion. Zero LDS, full occupancy, grid-stride.
// SINGLE CHANGE vs round 3: nontemporal output stores (write-once stream,
// bypass L2 write-allocate so it doesn't fight the hot table lines).
__global__ __launch_bounds__(256) void expand_kernel(
    const unsigned* __restrict__ counts,
    const float* __restrict__ table,
    float* __restrict__ out) {
    const unsigned t = blockIdx.x * 256u + threadIdx.x;  // 0 .. 2^20-1
    const f32x4* __restrict__ t4 = (const f32x4*)table;
    f32x4* __restrict__ out4 = (f32x4*)out;
#pragma unroll
    for (int it = 0; it < 8; ++it) {
        const unsigned g = t + (unsigned)it * (4096u * 256u);  // float4 index
        const unsigned r = g & 15u;
        const unsigned idx = g >> 4;          // channel*BL + position
        const unsigned w = counts[idx];       // broadcast within 16-lane group
        const unsigned c0 = w & 0xFFFFu;
        const unsigned c1 = w >> 16;
        const f32x4 o = t4[c0 * 16u + r] + t4[c1 * 16u + r];  // L1-hot rows
        __builtin_nontemporal_store(o, &out4[g]);  // coalesced, 1 KB/wave
    }
}

extern "C" void kernel_launch(void* const* d_in, const int* in_sizes, int n_in,
                              void* d_out, int out_size, void* d_ws, size_t ws_size,
                              hipStream_t stream) {
    const int*   src_ids = (const int*)d_in[0];
    const int*   dst_ids = (const int*)d_in[1];
    const float* W1      = (const float*)d_in[2];
    const float* b1      = (const float*)d_in[3];
    const float* W2      = (const float*)d_in[4];
    const float* b2      = (const float*)d_in[5];
    // d_in[6] = num_nodes scalar (20000) — hardcoded as Vn.

    float*    table  = (float*)d_ws;                   // 513*64*4 = 131 KB
    unsigned* counts = (unsigned*)(table + 513 * Fn);  // 2*BL*4 = 2 MB

    prep_kernel<<<Bn, 256, 0, stream>>>(src_ids, dst_ids, W1, b1, W2, b2,
                                        table, counts);
    // 2*BL positions * 16 float4-slots = 8,388,608 float4s = 4096*256*8.
    expand_kernel<<<4096, 256, 0, stream>>>(counts, table, (float*)d_out);
}

// Round 5
// 149.592 us; speedup vs baseline: 1.0915x; 1.0915x over previous
//
#include <hip/hip_runtime.h>

// Problem constants (fixed by setup_inputs).
constexpr int Bn = 512;               // batch rows
constexpr int Ln = 512;               // sequence length
constexpr int Fn = 64;                // feature dim
constexpr int Vn = 20000;             // num_nodes (vocab)
constexpr int HWORDS = (Vn + 2) / 3;  // 10-bit-packed histogram words (3 counts/u32)
constexpr int BL = Bn * Ln;           // positions per channel = 262144 = 2^18
constexpr int TROWS = 16;             // table rows cached in LDS (counts here are <=6)

// clang-native float4 (HIP's float4 is a class the nontemporal builtin rejects)
typedef float f32x4 __attribute__((ext_vector_type(4)));

__device__ __forceinline__ unsigned hist_get(const unsigned* __restrict__ h, int v) {
    const int w = v / 3;
    const int f = v - w * 3;
    return (h[w] >> (10 * f)) & 0x3FFu;
}

// Exact fallback for counts >= TROWS (never taken for this input, kept for
// correctness on arbitrary data): table[c][4r..4r+3].
__device__ __noinline__ f32x4 table_row4(float v, unsigned r,
                                         const float* __restrict__ W1,
                                         const float* __restrict__ b1,
                                         const float* __restrict__ W2,
                                         const float* __restrict__ b2) {
    const int j0 = (int)r * 4;
    f32x4 acc = { b2[j0], b2[j0 + 1], b2[j0 + 2], b2[j0 + 3] };
    for (int i = 0; i < Fn; ++i) {
        const float h = fmaxf(fmaf(v, W1[i], b1[i]), 0.0f);
        acc.x = fmaf(h, W2[i * Fn + j0 + 0], acc.x);
        acc.y = fmaf(h, W2[i * Fn + j0 + 1], acc.y);
        acc.z = fmaf(h, W2[i * Fn + j0 + 2], acc.z);
        acc.w = fmaf(h, W2[i * Fn + j0 + 3], acc.w);
    }
    return acc;
}

// Single launch: per-row LDS histograms + in-block 16-row MLP table ->
// packed per-position counts in LDS -> direct coalesced float4 expansion.
// No workspace, no inter-kernel gaps, no counts/table global traffic.
// LDS: 2*6667*4 + 2*512*4 + 16*64*4 = 61.4 KB -> 2 blocks/CU.
__global__ __launch_bounds__(512) void fused_kernel(
    const int* __restrict__ src_ids,
    const int* __restrict__ dst_ids,
    const float* __restrict__ W1,
    const float* __restrict__ b1,
    const float* __restrict__ W2,
    const float* __restrict__ b2,
    float* __restrict__ out) {
    __shared__ unsigned hs[HWORDS];
    __shared__ unsigned hd[HWORDS];
    __shared__ unsigned pc[2 * Ln];     // packed counts: [a][l]
    __shared__ float tl[TROWS][Fn];     // local table rows 0..15 (4 KB)

    const int b = blockIdx.x;
    const int tid = threadIdx.x;

    for (int i = tid; i < HWORDS; i += 512) { hs[i] = 0u; hd[i] = 0u; }

    // Ln == blockDim.x == 512: each thread owns exactly one position.
    const int s = src_ids[b * Ln + tid];
    const int d = dst_ids[b * Ln + tid];

    // Local table rows 0..15 while the id loads are in flight:
    // thread (tid) computes col j = tid&63 of rows (tid>>6) and (tid>>6)+8.
    // table[v][j] = b2[j] + sum_i relu(v*W1[i]+b1[i]) * W2[i*Fn+j]
    {
        const int j = tid & 63;
#pragma unroll
        for (int k = 0; k < 2; ++k) {
            const int v = (tid >> 6) + 8 * k;
            float acc = b2[j];
#pragma unroll
            for (int i = 0; i < Fn; ++i) {
                const float h = fmaxf(fmaf((float)v, W1[i], b1[i]), 0.0f);
                acc = fmaf(h, W2[i * Fn + j], acc);
            }
            tl[v][j] = acc;
        }
    }
    __syncthreads();

    {
        int w;
        w = s / 3; atomicAdd(&hs[w], 1u << (10 * (s - w * 3)));
        w = d / 3; atomicAdd(&hd[w], 1u << (10 * (d - w * 3)));
    }
    __syncthreads();

    // Packed counts: (count in src row) | (count in dst row) << 16.
    // Padding id 0 -> 0 in both channels (matches reference masking).
    {
        unsigned ws = 0u, wd = 0u;
        if (s != 0) ws = hist_get(hs, s) | (hist_get(hd, s) << 16);
        if (d != 0) wd = hist_get(hs, d) | (hist_get(hd, d) << 16);
        pc[tid] = ws;
        pc[Ln + tid] = wd;
    }
    __syncthreads();

    // Expansion: 2 channels * 512 positions * 16 float4-slots = 16384 tasks,
    // 32/thread. Per wave: 4 consecutive idx * 16 slots = 1 KB contiguous
    // stores. Table reads come from LDS (tl), counts from LDS (pc).
    const f32x4* __restrict__ tl4 = (const f32x4*)&tl[0][0];
    f32x4* __restrict__ out4 = (f32x4*)out;
    const unsigned row16 = (unsigned)b * (Ln * 16u);  // b*8192 float4s
#pragma unroll 4
    for (int it = 0; it < 32; ++it) {
        const unsigned g = (unsigned)it * 512u + tid;  // 0..16383
        const unsigned r = g & 15u;
        const unsigned idx = g >> 4;         // a*Ln + l, 0..1023
        const unsigned a = idx >> 9;
        const unsigned w = pc[idx];          // broadcast within 16-lane group
        const unsigned c0 = w & 0xFFFFu;
        const unsigned c1 = w >> 16;
        f32x4 t0, t1;
        if (c0 < (unsigned)TROWS) t0 = tl4[c0 * 16u + r];
        else                      t0 = table_row4((float)c0, r, W1, b1, W2, b2);
        if (c1 < (unsigned)TROWS) t1 = tl4[c1 * 16u + r];
        else                      t1 = table_row4((float)c1, r, W1, b1, W2, b2);
        const f32x4 o = t0 + t1;
        // global float4 index: a*(BL*16) + b*8192 + (g & 8191)
        out4[a * (BL * 16u) + row16 + (g & 8191u)] = o;
    }
}

extern "C" void kernel_launch(void* const* d_in, const int* in_sizes, int n_in,
                              void* d_out, int out_size, void* d_ws, size_t ws_size,
                              hipStream_t stream) {
    const int*   src_ids = (const int*)d_in[0];
    const int*   dst_ids = (const int*)d_in[1];
    const float* W1      = (const float*)d_in[2];
    const float* b1      = (const float*)d_in[3];
    const float* W2      = (const float*)d_in[4];
    const float* b2      = (const float*)d_in[5];
    // d_in[6] = num_nodes scalar (20000) — hardcoded as Vn.
    // Workspace unused: everything lives in LDS now.

    fused_kernel<<<Bn, 512, 0, stream>>>(src_ids, dst_ids, W1, b1, W2, b2,
                                         (float*)d_out);
}